// Round 6
// baseline (294.955 us; speedup 1.0000x reference)
//
#include <hip/hip_runtime.h>

#define NN 4096
#define FF 64
#define OO 64
#define KK 5
#define BB 8

typedef unsigned short bf16_t;
typedef __attribute__((ext_vector_type(8))) short short8;
typedef __attribute__((ext_vector_type(4))) float floatx4;

__device__ __forceinline__ unsigned short f2bf(float x) {
  unsigned int u = __float_as_uint(x);
  return (unsigned short)((u + 0x7fffu + ((u >> 16) & 1u)) >> 16); // RNE
}
__device__ __forceinline__ float bf2f(unsigned short h) {
  return __uint_as_float(((unsigned int)h) << 16);
}
__device__ __forceinline__ bool is_nan(float x) {
  return (__float_as_uint(x) & 0x7fffffffu) > 0x7f800000u; // raw-bits, fast-math immune
}
__device__ __forceinline__ void gld16(const void* g, void* l) {
  __builtin_amdgcn_global_load_lds(
      (__attribute__((address_space(1))) const unsigned int*)g,
      (__attribute__((address_space(3))) unsigned int*)l, 16, 0, 0);
}

union S8 { short8 s; int4 i; uint4 u; };

// sum two bf16x8 fragments in f32, repack to bf16 (split-K reduce)
__device__ __forceinline__ short8 addbf(short8 x, short8 y) {
  S8 a, b, r;
  a.s = x; b.s = y;
#pragma unroll
  for (int e = 0; e < 8; ++e)
    r.s[e] = (short)f2bf(bf2f((unsigned short)a.s[e]) + bf2f((unsigned short)b.s[e]));
  return r.s;
}

// ---------------- front: cast2 (blocks 0..8191) | stage1 (8192..8703) | prep (8704..8783) ----------------
// All three are mutually independent (stage1 inlines exp(-sigma)); one dispatch.
__global__ __launch_bounds__(256) void front_kernel(
    const float* __restrict__ shift, const float* __restrict__ A2,
    const float* __restrict__ feat, const float* __restrict__ W,
    const float* __restrict__ pi, const float* __restrict__ mu,
    const float* __restrict__ sigma,
    bf16_t* __restrict__ shift_bf, bf16_t* __restrict__ A2_bf,
    bf16_t* __restrict__ BigBT, float* __restrict__ gamma,
    bf16_t* __restrict__ WTb, bf16_t* __restrict__ EkT, bf16_t* __restrict__ DkT) {
  __shared__ bf16_t F0s[64][66];
  __shared__ bf16_t Ms[64][66];
  int bb = blockIdx.x;

  if (bb < 8192) {
    // ---- cast shift & A2 to bf16 ----
    int i = (bb * 256 + threadIdx.x) * 8;
    float4 a = *(const float4*)(shift + i);
    float4 b = *(const float4*)(shift + i + 4);
    union { unsigned short h[8]; uint4 v; } r;
    r.h[0] = f2bf(a.x); r.h[1] = f2bf(a.y); r.h[2] = f2bf(a.z); r.h[3] = f2bf(a.w);
    r.h[4] = f2bf(b.x); r.h[5] = f2bf(b.y); r.h[6] = f2bf(b.z); r.h[7] = f2bf(b.w);
    *(uint4*)(shift_bf + i) = r.v;
    a = *(const float4*)(A2 + i);
    b = *(const float4*)(A2 + i + 4);
    r.h[0] = f2bf(a.x); r.h[1] = f2bf(a.y); r.h[2] = f2bf(a.z); r.h[3] = f2bf(a.w);
    r.h[4] = f2bf(b.x); r.h[5] = f2bf(b.y); r.h[6] = f2bf(b.z); r.h[7] = f2bf(b.w);
    *(uint4*)(A2_bf + i) = r.v;
    return;
  }

  if (bb >= 8704) {
    // ---- prep: W^T, E_k^T=(mu.W)^T, D_k^T=(var.W^2)^T (feeds stage2 only) ----
    int t = (bb - 8704) * 256 + threadIdx.x; // [0, 20480)
    if (t < FF * OO) {
      int o = t >> 6, f = t & 63;
      WTb[t] = f2bf(W[f * OO + o]);
    }
    int k = t >> 12, o = (t >> 6) & 63, f = t & 63;
    if (k < KK) {
      float w = W[f * OO + o];
      EkT[t] = f2bf(mu[k * FF + f] * w);
      DkT[t] = f2bf(expf(sigma[k * FF + f]) * w * w);
    }
    return;
  }

  // ---- stage1: sanitize + NaN mask (transposed bf16) + gamma ----
  int blk = bb - 8192;
  int t = threadIdx.x;
  int b = blk >> 6;
  int n0 = (blk & 63) << 6;
  int r = t >> 2, c4 = t & 3;
  const float* frow = feat + ((size_t)b * NN + n0 + r) * FF + c4 * 16;

  float s[KK] = {0.f, 0.f, 0.f, 0.f, 0.f};
#pragma unroll
  for (int ch = 0; ch < 4; ++ch) {
    float4 v4 = *(const float4*)(frow + ch * 4);
    float vv[4] = {v4.x, v4.y, v4.z, v4.w};
#pragma unroll
    for (int e = 0; e < 4; ++e) {
      int f = c4 * 16 + ch * 4 + e;
      bool nb = is_nan(vv[e]);
      float x = nb ? 0.f : vv[e];
      F0s[r][f] = nb ? (bf16_t)0 : f2bf(x);
      Ms[r][f] = nb ? (bf16_t)0x3F80 : (bf16_t)0; // bf16(1.0)
#pragma unroll
      for (int k = 0; k < KK; ++k) {
        float d = nb ? 0.f : (x - mu[k * FF + f]);
        s[k] = fmaf(d * d * expf(-sigma[k * FF + f]), 1.0f, s[k]);
      }
    }
  }
#pragma unroll
  for (int k = 0; k < KK; ++k) {
    s[k] += __shfl_xor(s[k], 1);
    s[k] += __shfl_xor(s[k], 2);
  }
  if (c4 == 0) {
    float l[KK], mx = -3.0e38f;
#pragma unroll
    for (int k = 0; k < KK; ++k) { l[k] = pi[k] - 0.5f * s[k]; mx = fmaxf(mx, l[k]); }
    float ek[KK], sum = 0.f;
#pragma unroll
    for (int k = 0; k < KK; ++k) { ek[k] = expf(l[k] - mx); sum += ek[k]; }
    float inv = 1.0f / sum;
#pragma unroll
    for (int k = 0; k < KK; ++k)
      gamma[((size_t)(b * KK + k)) * NN + n0 + r] = ek[k] * inv;
  }
  __syncthreads();
#pragma unroll
  for (int it = 0; it < 2; ++it) {
    int f = it * 32 + (t >> 3);
    int nc = t & 7;
    union { bf16_t h[8]; uint4 v; } p;
#pragma unroll
    for (int e = 0; e < 8; ++e) p.h[e] = F0s[nc * 8 + e][f];
    *(uint4*)(BigBT + ((size_t)(b * 128 + f)) * NN + n0 + nc * 8) = p.v;
#pragma unroll
    for (int e = 0; e < 8; ++e) p.h[e] = Ms[nc * 8 + e][f];
    *(uint4*)(BigBT + ((size_t)(b * 128 + 64 + f)) * NN + n0 + nc * 8) = p.v;
  }
}

// ---------------- big GEMM, split-K x2, XCD-locality mapping ----------------
// x = bid & 7 (XCD heuristic), j = bid >> 3.
// j <  64: QR job — tile_c = x (B-panel pinned per XCD), tile_m = j>>1, kh = j&1.
// j >= 64: P  job — tile_m = j-64, tile_c = x&3, kh = x>>2.
// 768 blocks = exactly 3 per CU.
__global__ __launch_bounds__(256) void gemm_bt_kernel(
    const bf16_t* __restrict__ A0, const bf16_t* __restrict__ BigBT, bf16_t* __restrict__ C0,
    const bf16_t* __restrict__ A1, bf16_t* __restrict__ C1) {
  __shared__ bf16_t As[128 * 64];
  __shared__ bf16_t Bs[128 * 64];
  int x = blockIdx.x & 7;
  int j = blockIdx.x >> 3;
  const bf16_t* A;
  bf16_t* C;
  int tile_m, tile_c, kh, Cld;
  bool isP = (j >= 64);
  if (!isP) {
    A = A0; tile_c = x; tile_m = j >> 1; kh = j & 1; Cld = 1024;
    C = C0 + (size_t)kh * (NN * 1024);
  } else {
    A = A1; tile_m = j - 64; tile_c = x & 3; kh = x >> 2; Cld = 512;
    C = C1 + (size_t)kh * (NN * 512);
  }

  int tid = threadIdx.x;
  int wave = tid >> 6, lane = tid & 63;
  int wm = wave >> 1, wc = wave & 1;

  int srow = wave * 32 + (lane >> 3);
  int scol = (((lane & 7) ^ (lane >> 3)) << 3); // XOR-swizzled source chunk
  const bf16_t* Ag = A + (size_t)(tile_m * 128 + srow) * NN + scol;
  int browi;
  if (!isP) {
    browi = tile_c * 128 + srow;
  } else {
    int c2 = tile_c * 128 + srow; // P's B row c2 = b*64+f -> BigBT M row b*128+64+f
    browi = ((c2 >> 6) << 7) + 64 + (c2 & 63);
  }
  const bf16_t* Bg = BigBT + (size_t)browi * NN + scol;
  bf16_t* AsW = &As[(wave * 32) * 64];
  bf16_t* BsW = &Bs[(wave * 32) * 64];

  floatx4 acc[4][4];
#pragma unroll
  for (int i = 0; i < 4; ++i)
#pragma unroll
    for (int j2 = 0; j2 < 4; ++j2) acc[i][j2] = (floatx4){0.f, 0.f, 0.f, 0.f};

  int ml = lane & 15;
  int q = lane >> 4;
  int sw = ml & 7;

#pragma unroll 1
  for (int kt = kh * 32; kt < kh * 32 + 32; ++kt) {
    int k0 = kt * 64;
    __syncthreads();
#pragma unroll
    for (int i = 0; i < 4; ++i) {
      gld16(Ag + (size_t)(i * 8) * NN + k0, AsW + (i * 8) * 64);
      gld16(Bg + (size_t)(i * 8) * NN + k0, BsW + (i * 8) * 64);
    }
    __syncthreads();
#pragma unroll
    for (int ks = 0; ks < 2; ++ks) {
      int chunk = (((ks * 4 + q) ^ sw) << 3);
      short8 a[4], bb[4];
#pragma unroll
      for (int i = 0; i < 4; ++i)
        a[i] = *(const short8*)&As[(wm * 64 + i * 16 + ml) * 64 + chunk];
#pragma unroll
      for (int j2 = 0; j2 < 4; ++j2)
        bb[j2] = *(const short8*)&Bs[(wc * 64 + j2 * 16 + ml) * 64 + chunk];
#pragma unroll
      for (int i = 0; i < 4; ++i)
#pragma unroll
        for (int j2 = 0; j2 < 4; ++j2)
          acc[i][j2] = __builtin_amdgcn_mfma_f32_16x16x32_bf16(a[i], bb[j2], acc[i][j2], 0, 0, 0);
    }
  }

  int colb = tile_c * 128 + wc * 64 + ml;
#pragma unroll
  for (int i = 0; i < 4; ++i) {
    int mrow = tile_m * 128 + wm * 64 + i * 16 + q * 4;
#pragma unroll
    for (int j2 = 0; j2 < 4; ++j2)
#pragma unroll
      for (int r = 0; r < 4; ++r)
        C[(size_t)(mrow + r) * Cld + colb + j2 * 16] = f2bf(acc[i][j2][r]);
  }
}

// ---------------- stage 2: split-K reduce; cx=QW+R@Ek, cc=P@Dk; ex_relu*gamma k-sum ----------------
__global__ __launch_bounds__(256) void stage2_kernel(
    const bf16_t* __restrict__ QRp, const bf16_t* __restrict__ Pp,
    const bf16_t* __restrict__ WTb, const bf16_t* __restrict__ EkT,
    const bf16_t* __restrict__ DkT, const float* __restrict__ gamma,
    float* __restrict__ out) {
  const bf16_t* QR1 = QRp + (size_t)NN * 1024;
  const bf16_t* Pp1 = Pp + (size_t)NN * 512;
  int t = threadIdx.x;
  int b = blockIdx.x >> 6;
  int n0 = (blockIdx.x & 63) << 6;
  int w = t >> 6, lane = t & 63, m = lane & 15, q = lane >> 4;
  int n = n0 + w * 16 + m;

  short8 Qf[2], Rf[2], Pf[2], wfr[4][2];
#pragma unroll
  for (int ks = 0; ks < 2; ++ks) {
    size_t oq = (size_t)n * 1024 + b * 128 + ks * 32 + q * 8;
    size_t op = (size_t)n * 512 + b * 64 + ks * 32 + q * 8;
    Qf[ks] = addbf(*(const short8*)(QRp + oq), *(const short8*)(QR1 + oq));
    Rf[ks] = addbf(*(const short8*)(QRp + oq + 64), *(const short8*)(QR1 + oq + 64));
    Pf[ks] = addbf(*(const short8*)(Pp + op), *(const short8*)(Pp1 + op));
  }
#pragma unroll
  for (int ot = 0; ot < 4; ++ot)
#pragma unroll
    for (int ks = 0; ks < 2; ++ks)
      wfr[ot][ks] = *(const short8*)(WTb + (ot * 16 + m) * 64 + ks * 32 + q * 8);

  floatx4 z = (floatx4){0.f, 0.f, 0.f, 0.f};
  floatx4 QW[4], osum[4];
#pragma unroll
  for (int ot = 0; ot < 4; ++ot) {
    QW[ot] = __builtin_amdgcn_mfma_f32_16x16x32_bf16(Qf[0], wfr[ot][0], z, 0, 0, 0);
    QW[ot] = __builtin_amdgcn_mfma_f32_16x16x32_bf16(Qf[1], wfr[ot][1], QW[ot], 0, 0, 0);
    osum[ot] = z;
  }

#pragma unroll
  for (int k = 0; k < KK; ++k) {
    float4 g4 = *(const float4*)(gamma + ((size_t)(b * KK + k)) * NN + n0 + w * 16 + q * 4);
    float gg[4] = {g4.x, g4.y, g4.z, g4.w};
#pragma unroll
    for (int ot = 0; ot < 4; ++ot) {
      const bf16_t* ek = EkT + ((k * 64 + ot * 16 + m) * 64) + q * 8;
      const bf16_t* dk = DkT + ((k * 64 + ot * 16 + m) * 64) + q * 8;
      short8 e0 = *(const short8*)ek, e1 = *(const short8*)(ek + 32);
      short8 d0 = *(const short8*)dk, d1 = *(const short8*)(dk + 32);
      floatx4 cx4 = __builtin_amdgcn_mfma_f32_16x16x32_bf16(Rf[0], e0, QW[ot], 0, 0, 0);
      cx4 = __builtin_amdgcn_mfma_f32_16x16x32_bf16(Rf[1], e1, cx4, 0, 0, 0);
      floatx4 cc4 = __builtin_amdgcn_mfma_f32_16x16x32_bf16(Pf[0], d0, z, 0, 0, 0);
      cc4 = __builtin_amdgcn_mfma_f32_16x16x32_bf16(Pf[1], d1, cc4, 0, 0, 0);
#pragma unroll
      for (int r = 0; r < 4; ++r) {
        float mm = cx4[r];
        float v = cc4[r];
        float sd = sqrtf(fmaxf(v, 0.f));
        float zz = mm / (sd > 0.f ? sd : 1.f);
        float pdf = expf(-0.5f * zz * zz) * 0.3989422804014327f;
        float cdf = 0.5f * (1.f + erff(zz * 0.7071067811865476f));
        float ex = sd > 0.f ? fmaf(mm, cdf, sd * pdf) : fmaxf(mm, 0.f);
        osum[ot][r] = fmaf(gg[r], ex, osum[ot][r]);
      }
    }
  }

#pragma unroll
  for (int ot = 0; ot < 4; ++ot)
#pragma unroll
    for (int r = 0; r < 4; ++r)
      out[((size_t)b * NN + n0 + w * 16 + q * 4 + r) * OO + ot * 16 + m] = osum[ot][r];
}

extern "C" void kernel_launch(void* const* d_in, const int* in_sizes, int n_in,
                              void* d_out, int out_size, void* d_ws, size_t ws_size,
                              hipStream_t stream) {
  const float* shift = (const float*)d_in[0];
  const float* A2    = (const float*)d_in[1];
  const float* feat  = (const float*)d_in[2];
  const float* W     = (const float*)d_in[3];
  const float* pi    = (const float*)d_in[4];
  const float* mu    = (const float*)d_in[5];
  const float* sigma = (const float*)d_in[6];
  float* out = (float*)d_out;

  char* ws = (char*)d_ws;
  bf16_t* shift_bf = (bf16_t*)(ws + 0);          // 33,554,432
  bf16_t* A2_bf    = (bf16_t*)(ws + 33554432);   // 33,554,432
  bf16_t* BigBT    = (bf16_t*)(ws + 67108864);   //  8,388,608  [1024][4096]
  bf16_t* QRp      = (bf16_t*)(ws + 75497472);   // 16,777,216  [2][4096][1024]
  bf16_t* Pp       = (bf16_t*)(ws + 92274688);   //  8,388,608  [2][4096][512]
  float*  gam      = (float*) (ws + 100663296);  //    655,360  [B,K,N]
  bf16_t* WTb      = (bf16_t*)(ws + 101318656);  //      8,192
  bf16_t* EkT      = (bf16_t*)(ws + 101326848);  //     40,960
  bf16_t* DkT      = (bf16_t*)(ws + 101367808);  //     40,960  (end ~96.7 MiB)

  front_kernel<<<8784, 256, 0, stream>>>(shift, A2, feat, W, pi, mu, sigma,
                                         shift_bf, A2_bf, BigBT, gam, WTb, EkT, DkT);
  gemm_bt_kernel<<<768, 256, 0, stream>>>(shift_bf, BigBT, QRp, A2_bf, Pp);
  stage2_kernel<<<512, 256, 0, stream>>>(QRp, Pp, WTb, EkT, DkT, gam, out);
}

// Round 7
// 272.566 us; speedup vs baseline: 1.0821x; 1.0821x over previous
//
#include <hip/hip_runtime.h>

#define NN 4096
#define FF 64
#define OO 64
#define KK 5
#define BB 8

typedef unsigned short bf16_t;
typedef __attribute__((ext_vector_type(8))) short short8;
typedef __attribute__((ext_vector_type(4))) float floatx4;

__device__ __forceinline__ unsigned short f2bf(float x) {
  unsigned int u = __float_as_uint(x);
  return (unsigned short)((u + 0x7fffu + ((u >> 16) & 1u)) >> 16); // RNE
}
__device__ __forceinline__ float bf2f(unsigned short h) {
  return __uint_as_float(((unsigned int)h) << 16);
}
__device__ __forceinline__ bool is_nan(float x) {
  return (__float_as_uint(x) & 0x7fffffffu) > 0x7f800000u; // raw-bits, fast-math immune
}
__device__ __forceinline__ void gld16(const void* g, void* l) {
  __builtin_amdgcn_global_load_lds(
      (__attribute__((address_space(1))) const unsigned int*)g,
      (__attribute__((address_space(3))) unsigned int*)l, 16, 0, 0);
}

union S8 { short8 s; int4 i; uint4 u; };

// sum two bf16x8 fragments in f32, repack to bf16 (split-K reduce)
__device__ __forceinline__ short8 addbf(short8 x, short8 y) {
  S8 a, b, r;
  a.s = x; b.s = y;
#pragma unroll
  for (int e = 0; e < 8; ++e)
    r.s[e] = (short)f2bf(bf2f((unsigned short)a.s[e]) + bf2f((unsigned short)b.s[e]));
  return r.s;
}

// ---------------- front: stage1 (0..511) | cast2 (512..8703) | prep (8704..8783) ----------------
// stage1 blocks FIRST so their VALU work overlaps the HBM-bound cast blocks
// (R6 had them last -> serial tail). prep feeds stage2 only (2 dispatches later).
__global__ __launch_bounds__(256) void front_kernel(
    const float* __restrict__ shift, const float* __restrict__ A2,
    const float* __restrict__ feat, const float* __restrict__ W,
    const float* __restrict__ pi, const float* __restrict__ mu,
    const float* __restrict__ sigma,
    bf16_t* __restrict__ shift_bf, bf16_t* __restrict__ A2_bf,
    bf16_t* __restrict__ BigBT, float* __restrict__ gamma,
    bf16_t* __restrict__ WTb, bf16_t* __restrict__ EkT, bf16_t* __restrict__ DkT) {
  __shared__ bf16_t F0s[64][66];
  __shared__ bf16_t Ms[64][66];
  int bb = blockIdx.x;

  if (bb >= 512 && bb < 8704) {
    // ---- cast shift & A2 to bf16 (HBM-bound bulk) ----
    int i = ((bb - 512) * 256 + threadIdx.x) * 8;
    float4 a = *(const float4*)(shift + i);
    float4 b = *(const float4*)(shift + i + 4);
    union { unsigned short h[8]; uint4 v; } r;
    r.h[0] = f2bf(a.x); r.h[1] = f2bf(a.y); r.h[2] = f2bf(a.z); r.h[3] = f2bf(a.w);
    r.h[4] = f2bf(b.x); r.h[5] = f2bf(b.y); r.h[6] = f2bf(b.z); r.h[7] = f2bf(b.w);
    *(uint4*)(shift_bf + i) = r.v;
    a = *(const float4*)(A2 + i);
    b = *(const float4*)(A2 + i + 4);
    r.h[0] = f2bf(a.x); r.h[1] = f2bf(a.y); r.h[2] = f2bf(a.z); r.h[3] = f2bf(a.w);
    r.h[4] = f2bf(b.x); r.h[5] = f2bf(b.y); r.h[6] = f2bf(b.z); r.h[7] = f2bf(b.w);
    *(uint4*)(A2_bf + i) = r.v;
    return;
  }

  if (bb >= 8704) {
    // ---- prep: W^T, E_k^T=(mu.W)^T, D_k^T=(var.W^2)^T ----
    int t = (bb - 8704) * 256 + threadIdx.x; // [0, 20480)
    if (t < FF * OO) {
      int o = t >> 6, f = t & 63;
      WTb[t] = f2bf(W[f * OO + o]);
    }
    int k = t >> 12, o = (t >> 6) & 63, f = t & 63;
    if (k < KK) {
      float w = W[f * OO + o];
      EkT[t] = f2bf(mu[k * FF + f] * w);
      DkT[t] = f2bf(__expf(sigma[k * FF + f]) * w * w);
    }
    return;
  }

  // ---- stage1: sanitize + NaN mask (transposed bf16) + gamma ----
  int t = threadIdx.x;
  int b = bb >> 6;
  int n0 = (bb & 63) << 6;
  int r = t >> 2, c4 = t & 3; // row, 16-wide f chunk
  const float* frow = feat + ((size_t)b * NN + n0 + r) * FF + c4 * 16;

  // load this thread's 16 feature values; sanitize + write LDS tiles
  float vv[16];
  bool nb[16];
#pragma unroll
  for (int ch = 0; ch < 4; ++ch) {
    float4 v4 = *(const float4*)(frow + ch * 4);
    vv[ch * 4 + 0] = v4.x; vv[ch * 4 + 1] = v4.y;
    vv[ch * 4 + 2] = v4.z; vv[ch * 4 + 3] = v4.w;
  }
#pragma unroll
  for (int e = 0; e < 16; ++e) {
    int f = c4 * 16 + e;
    nb[e] = is_nan(vv[e]);
    if (nb[e]) vv[e] = 0.f;
    F0s[r][f] = nb[e] ? (bf16_t)0 : f2bf(vv[e]);
    Ms[r][f] = nb[e] ? (bf16_t)0x3F80 : (bf16_t)0; // bf16(1.0)
  }

  // gamma: per-k pass, expf hoisted out of the element loop (16 __expf per k)
  float s[KK];
#pragma unroll
  for (int k = 0; k < KK; ++k) {
    const float* murow = mu + k * FF + c4 * 16;
    const float* sgrow = sigma + k * FF + c4 * 16;
    float acc = 0.f;
#pragma unroll
    for (int ch = 0; ch < 4; ++ch) {
      float4 m4 = *(const float4*)(murow + ch * 4);
      float4 g4 = *(const float4*)(sgrow + ch * 4);
      float mm[4] = {m4.x, m4.y, m4.z, m4.w};
      float gg[4] = {g4.x, g4.y, g4.z, g4.w};
#pragma unroll
      for (int e2 = 0; e2 < 4; ++e2) {
        int e = ch * 4 + e2;
        float d = nb[e] ? 0.f : (vv[e] - mm[e2]);
        acc = fmaf(d * d, __expf(-gg[e2]), acc);
      }
    }
    s[k] = acc;
  }
#pragma unroll
  for (int k = 0; k < KK; ++k) {
    s[k] += __shfl_xor(s[k], 1);
    s[k] += __shfl_xor(s[k], 2);
  }
  if (c4 == 0) {
    float l[KK], mx = -3.0e38f;
#pragma unroll
    for (int k = 0; k < KK; ++k) { l[k] = pi[k] - 0.5f * s[k]; mx = fmaxf(mx, l[k]); }
    float ek[KK], sum = 0.f;
#pragma unroll
    for (int k = 0; k < KK; ++k) { ek[k] = __expf(l[k] - mx); sum += ek[k]; }
    float inv = 1.0f / sum;
#pragma unroll
    for (int k = 0; k < KK; ++k)
      gamma[((size_t)(b * KK + k)) * NN + n0 + r] = ek[k] * inv;
  }
  __syncthreads();
  // transposed stores: 8-lane groups write contiguous 128B runs
#pragma unroll
  for (int it = 0; it < 2; ++it) {
    int f = it * 32 + (t >> 3);
    int nc = t & 7;
    union { bf16_t h[8]; uint4 v; } p;
#pragma unroll
    for (int e = 0; e < 8; ++e) p.h[e] = F0s[nc * 8 + e][f];
    *(uint4*)(BigBT + ((size_t)(b * 128 + f)) * NN + n0 + nc * 8) = p.v;
#pragma unroll
    for (int e = 0; e < 8; ++e) p.h[e] = Ms[nc * 8 + e][f];
    *(uint4*)(BigBT + ((size_t)(b * 128 + 64 + f)) * NN + n0 + nc * 8) = p.v;
  }
}

// ---------------- big GEMM, split-K x2, XCD-locality mapping ----------------
__global__ __launch_bounds__(256) void gemm_bt_kernel(
    const bf16_t* __restrict__ A0, const bf16_t* __restrict__ BigBT, bf16_t* __restrict__ C0,
    const bf16_t* __restrict__ A1, bf16_t* __restrict__ C1) {
  __shared__ bf16_t As[128 * 64];
  __shared__ bf16_t Bs[128 * 64];
  int x = blockIdx.x & 7;
  int j = blockIdx.x >> 3;
  const bf16_t* A;
  bf16_t* C;
  int tile_m, tile_c, kh, Cld;
  bool isP = (j >= 64);
  if (!isP) {
    A = A0; tile_c = x; tile_m = j >> 1; kh = j & 1; Cld = 1024;
    C = C0 + (size_t)kh * (NN * 1024);
  } else {
    A = A1; tile_m = j - 64; tile_c = x & 3; kh = x >> 2; Cld = 512;
    C = C1 + (size_t)kh * (NN * 512);
  }

  int tid = threadIdx.x;
  int wave = tid >> 6, lane = tid & 63;
  int wm = wave >> 1, wc = wave & 1;

  int srow = wave * 32 + (lane >> 3);
  int scol = (((lane & 7) ^ (lane >> 3)) << 3); // XOR-swizzled source chunk
  const bf16_t* Ag = A + (size_t)(tile_m * 128 + srow) * NN + scol;
  int browi;
  if (!isP) {
    browi = tile_c * 128 + srow;
  } else {
    int c2 = tile_c * 128 + srow; // P's B row c2 = b*64+f -> BigBT M row b*128+64+f
    browi = ((c2 >> 6) << 7) + 64 + (c2 & 63);
  }
  const bf16_t* Bg = BigBT + (size_t)browi * NN + scol;
  bf16_t* AsW = &As[(wave * 32) * 64];
  bf16_t* BsW = &Bs[(wave * 32) * 64];

  floatx4 acc[4][4];
#pragma unroll
  for (int i = 0; i < 4; ++i)
#pragma unroll
    for (int j2 = 0; j2 < 4; ++j2) acc[i][j2] = (floatx4){0.f, 0.f, 0.f, 0.f};

  int ml = lane & 15;
  int q = lane >> 4;
  int sw = ml & 7;

#pragma unroll 1
  for (int kt = kh * 32; kt < kh * 32 + 32; ++kt) {
    int k0 = kt * 64;
    __syncthreads();
#pragma unroll
    for (int i = 0; i < 4; ++i) {
      gld16(Ag + (size_t)(i * 8) * NN + k0, AsW + (i * 8) * 64);
      gld16(Bg + (size_t)(i * 8) * NN + k0, BsW + (i * 8) * 64);
    }
    __syncthreads();
#pragma unroll
    for (int ks = 0; ks < 2; ++ks) {
      int chunk = (((ks * 4 + q) ^ sw) << 3);
      short8 a[4], bb[4];
#pragma unroll
      for (int i = 0; i < 4; ++i)
        a[i] = *(const short8*)&As[(wm * 64 + i * 16 + ml) * 64 + chunk];
#pragma unroll
      for (int j2 = 0; j2 < 4; ++j2)
        bb[j2] = *(const short8*)&Bs[(wc * 64 + j2 * 16 + ml) * 64 + chunk];
#pragma unroll
      for (int i = 0; i < 4; ++i)
#pragma unroll
        for (int j2 = 0; j2 < 4; ++j2)
          acc[i][j2] = __builtin_amdgcn_mfma_f32_16x16x32_bf16(a[i], bb[j2], acc[i][j2], 0, 0, 0);
    }
  }

  int colb = tile_c * 128 + wc * 64 + ml;
#pragma unroll
  for (int i = 0; i < 4; ++i) {
    int mrow = tile_m * 128 + wm * 64 + i * 16 + q * 4;
#pragma unroll
    for (int j2 = 0; j2 < 4; ++j2)
#pragma unroll
      for (int r = 0; r < 4; ++r)
        C[(size_t)(mrow + r) * Cld + colb + j2 * 16] = f2bf(acc[i][j2][r]);
  }
}

// ---------------- stage 2: split-K reduce; cx=QW+R@Ek, cc=P@Dk; ex_relu*gamma k-sum ----------------
__global__ __launch_bounds__(256) void stage2_kernel(
    const bf16_t* __restrict__ QRp, const bf16_t* __restrict__ Pp,
    const bf16_t* __restrict__ WTb, const bf16_t* __restrict__ EkT,
    const bf16_t* __restrict__ DkT, const float* __restrict__ gamma,
    float* __restrict__ out) {
  const bf16_t* QR1 = QRp + (size_t)NN * 1024;
  const bf16_t* Pp1 = Pp + (size_t)NN * 512;
  int t = threadIdx.x;
  int b = blockIdx.x >> 6;
  int n0 = (blockIdx.x & 63) << 6;
  int w = t >> 6, lane = t & 63, m = lane & 15, q = lane >> 4;
  int n = n0 + w * 16 + m;

  short8 Qf[2], Rf[2], Pf[2], wfr[4][2];
#pragma unroll
  for (int ks = 0; ks < 2; ++ks) {
    size_t oq = (size_t)n * 1024 + b * 128 + ks * 32 + q * 8;
    size_t op = (size_t)n * 512 + b * 64 + ks * 32 + q * 8;
    Qf[ks] = addbf(*(const short8*)(QRp + oq), *(const short8*)(QR1 + oq));
    Rf[ks] = addbf(*(const short8*)(QRp + oq + 64), *(const short8*)(QR1 + oq + 64));
    Pf[ks] = addbf(*(const short8*)(Pp + op), *(const short8*)(Pp1 + op));
  }
#pragma unroll
  for (int ot = 0; ot < 4; ++ot)
#pragma unroll
    for (int ks = 0; ks < 2; ++ks)
      wfr[ot][ks] = *(const short8*)(WTb + (ot * 16 + m) * 64 + ks * 32 + q * 8);

  floatx4 z = (floatx4){0.f, 0.f, 0.f, 0.f};
  floatx4 QW[4], osum[4];
#pragma unroll
  for (int ot = 0; ot < 4; ++ot) {
    QW[ot] = __builtin_amdgcn_mfma_f32_16x16x32_bf16(Qf[0], wfr[ot][0], z, 0, 0, 0);
    QW[ot] = __builtin_amdgcn_mfma_f32_16x16x32_bf16(Qf[1], wfr[ot][1], QW[ot], 0, 0, 0);
    osum[ot] = z;
  }

#pragma unroll
  for (int k = 0; k < KK; ++k) {
    float4 g4 = *(const float4*)(gamma + ((size_t)(b * KK + k)) * NN + n0 + w * 16 + q * 4);
    float gg[4] = {g4.x, g4.y, g4.z, g4.w};
#pragma unroll
    for (int ot = 0; ot < 4; ++ot) {
      const bf16_t* ek = EkT + ((k * 64 + ot * 16 + m) * 64) + q * 8;
      const bf16_t* dk = DkT + ((k * 64 + ot * 16 + m) * 64) + q * 8;
      short8 e0 = *(const short8*)ek, e1 = *(const short8*)(ek + 32);
      short8 d0 = *(const short8*)dk, d1 = *(const short8*)(dk + 32);
      floatx4 cx4 = __builtin_amdgcn_mfma_f32_16x16x32_bf16(Rf[0], e0, QW[ot], 0, 0, 0);
      cx4 = __builtin_amdgcn_mfma_f32_16x16x32_bf16(Rf[1], e1, cx4, 0, 0, 0);
      floatx4 cc4 = __builtin_amdgcn_mfma_f32_16x16x32_bf16(Pf[0], d0, z, 0, 0, 0);
      cc4 = __builtin_amdgcn_mfma_f32_16x16x32_bf16(Pf[1], d1, cc4, 0, 0, 0);
#pragma unroll
      for (int r = 0; r < 4; ++r) {
        float mm = cx4[r];
        float v = cc4[r];
        float sd = sqrtf(fmaxf(v, 0.f));
        float zz = mm / (sd > 0.f ? sd : 1.f);
        float pdf = __expf(-0.5f * zz * zz) * 0.3989422804014327f;
        float cdf = 0.5f * (1.f + erff(zz * 0.7071067811865476f));
        float ex = sd > 0.f ? fmaf(mm, cdf, sd * pdf) : fmaxf(mm, 0.f);
        osum[ot][r] = fmaf(gg[r], ex, osum[ot][r]);
      }
    }
  }

#pragma unroll
  for (int ot = 0; ot < 4; ++ot)
#pragma unroll
    for (int r = 0; r < 4; ++r)
      out[((size_t)b * NN + n0 + w * 16 + q * 4 + r) * OO + ot * 16 + m] = osum[ot][r];
}

extern "C" void kernel_launch(void* const* d_in, const int* in_sizes, int n_in,
                              void* d_out, int out_size, void* d_ws, size_t ws_size,
                              hipStream_t stream) {
  const float* shift = (const float*)d_in[0];
  const float* A2    = (const float*)d_in[1];
  const float* feat  = (const float*)d_in[2];
  const float* W     = (const float*)d_in[3];
  const float* pi    = (const float*)d_in[4];
  const float* mu    = (const float*)d_in[5];
  const float* sigma = (const float*)d_in[6];
  float* out = (float*)d_out;

  char* ws = (char*)d_ws;
  bf16_t* shift_bf = (bf16_t*)(ws + 0);          // 33,554,432
  bf16_t* A2_bf    = (bf16_t*)(ws + 33554432);   // 33,554,432
  bf16_t* BigBT    = (bf16_t*)(ws + 67108864);   //  8,388,608  [1024][4096]
  bf16_t* QRp      = (bf16_t*)(ws + 75497472);   // 16,777,216  [2][4096][1024]
  bf16_t* Pp       = (bf16_t*)(ws + 92274688);   //  8,388,608  [2][4096][512]
  float*  gam      = (float*) (ws + 100663296);  //    655,360  [B,K,N]
  bf16_t* WTb      = (bf16_t*)(ws + 101318656);  //      8,192
  bf16_t* EkT      = (bf16_t*)(ws + 101326848);  //     40,960
  bf16_t* DkT      = (bf16_t*)(ws + 101367808);  //     40,960  (end ~96.7 MiB)

  front_kernel<<<8784, 256, 0, stream>>>(shift, A2, feat, W, pi, mu, sigma,
                                         shift_bf, A2_bf, BigBT, gam, WTb, EkT, DkT);
  gemm_bt_kernel<<<768, 256, 0, stream>>>(shift_bf, BigBT, QRp, A2_bf, Pp);
  stage2_kernel<<<512, 256, 0, stream>>>(QRp, Pp, WTb, EkT, DkT, gam, out);
}